// Round 1
// baseline (1961.082 us; speedup 1.0000x reference)
//
#include <hip/hip_runtime.h>
#include <math.h>

// ---------------- workspace layout ----------------
// tw  : float2[4096]           W_8192^k = e^{-i pi k/4096}, k<4096
// V   : float2[16][64][4104]   rfft(a)/8192 per (h,d), bins 0..4096
// aT  : float2[16][32][8192]   packed a: aT[h][p][r] = (a[h][r][2p], a[h][r][2p+1])
// zx  : float2[128][32][4096]  packed x columns, reused in-place for output
static const size_t OFF_TW = 0;
static const size_t OFF_V  = 32768;
static const size_t OFF_AT = OFF_V  + (size_t)16 * 64 * 4104 * 8;
static const size_t OFF_ZX = OFF_AT + (size_t)16 * 32 * 8192 * 8;
static const size_t WS_NEED = OFF_ZX + (size_t)128 * 32 * 4096 * 8;

// ---------------- twiddle init ----------------
__global__ void __launch_bounds__(256) k_init_tw(float2* __restrict__ tw)
{
    int k = blockIdx.x * 256 + threadIdx.x;
    if (k < 4096) {
        double a = (double)k * (3.14159265358979323846 / 4096.0);
        tw[k] = make_float2((float)cos(a), (float)(-sin(a)));
    }
}

// ---------------- dpb MLP: wave per (r,d) evaluation ----------------
__device__ __forceinline__ float wsum64(float v)
{
    #pragma unroll
    for (int off = 32; off >= 1; off >>= 1) v += __shfl_xor(v, off);
    return v;
}

__device__ __forceinline__ float ln_relu(float x, int lane,
                                         const float* __restrict__ g,
                                         const float* __restrict__ be)
{
    float m = wsum64(x) * (1.0f / 64.0f);
    float c = x - m;
    float v = wsum64(c * c) * (1.0f / 64.0f);
    float y = c * rsqrtf(v + 1e-5f) * g[lane] + be[lane];
    return fmaxf(y, 0.0f);
}

__device__ __forceinline__ float mlp_layer(float act, int lane,
                                           const float* __restrict__ g,
                                           const float* __restrict__ be,
                                           const float* __restrict__ w,
                                           const float* __restrict__ b)
{
    float a = ln_relu(act, lane, g, be);
    float o = b[lane];
    #pragma unroll 8
    for (int k = 0; k < 64; ++k) {
        float ak = __shfl(a, k);
        o += ak * w[(k << 6) + lane];
    }
    return o;
}

__global__ void __launch_bounds__(256) k_dpb(
    const float* __restrict__ w0,  const float* __restrict__ b0,
    const float* __restrict__ g1,  const float* __restrict__ be1,
    const float* __restrict__ w1,  const float* __restrict__ b1,
    const float* __restrict__ g2,  const float* __restrict__ be2,
    const float* __restrict__ w2,  const float* __restrict__ b2,
    const float* __restrict__ g3,  const float* __restrict__ be3,
    const float* __restrict__ w3,  const float* __restrict__ b3,
    float* __restrict__ aTf)
{
    int wave = blockIdx.x * 4 + (threadIdx.x >> 6);
    int lane = threadIdx.x & 63;
    int r  = wave & 8191;     // position along the length-8192 'a' axis
    int dd = wave >> 13;      // dim index 0..63
    const float scale = (float)(1.0 / 262080.0);
    float u;
    if (r == 0 || r == 4096) u = 0.0f;
    else if (r < 4096)       u = (float)((r - 1) * 64 + dd + 1) * scale;
    else                     u = -(float)(262080 - ((r - 4097) * 64 + dd)) * scale;

    float act = u * w0[lane] + b0[lane];
    act = mlp_layer(act, lane, g1, be1, w1, b1);
    act = mlp_layer(act, lane, g2, be2, w2, b2);
    float a3 = ln_relu(act, lane, g3, be3);
    float o = b3[lane & 15];
    #pragma unroll 8
    for (int k = 0; k < 64; ++k) {
        float ak = __shfl(a3, k);
        o += ak * w3[(k << 4) + (lane & 15)];
    }
    if (lane < 16) {
        size_t idx = ((size_t)((lane << 5) + (dd >> 1)) * 8192 + r) * 2 + (dd & 1);
        aTf[idx] = o;
    }
}

// ---------------- 8192-pt complex FFT in LDS (256 threads) ----------------
// Natural-order in, natural-order out. 5 in-register radix-2 stages (on
// bit-reversed reads) + 4 LDS radix-4 stages (each a fused pair of radix-2
// stages, so plain 13-bit bit-reversal ordering is correct).
template<int L, bool INV>
__device__ __forceinline__ void reg_stage(float* xr, float* xi,
                                          const float2* __restrict__ tw)
{
    #pragma unroll
    for (int b = 0; b < 32; b += 2 * L) {
        #pragma unroll
        for (int j = 0; j < L; ++j) {
            float2 w = tw[j * (4096 / L)];
            float wr = w.x, wi = INV ? -w.y : w.y;
            int i0 = b + j, i1 = b + j + L;
            float tr = xr[i1] * wr - xi[i1] * wi;
            float ti = xr[i1] * wi + xi[i1] * wr;
            xr[i1] = xr[i0] - tr; xi[i1] = xi[i0] - ti;
            xr[i0] += tr;         xi[i0] += ti;
        }
    }
}

template<bool INV>
__device__ __forceinline__ void fft8192_lds(float* re, float* im,
                                            const float2* __restrict__ tw)
{
    const int t  = threadIdx.x;                       // 256 threads
    const int r8 = (int)(__brev((unsigned)t) >> 24);  // rev8(t)
    float xr[32], xi[32];
    #pragma unroll
    for (int i = 0; i < 32; ++i) {
        int r5 = (int)(__brev((unsigned)i) >> 27);    // rev5(i)
        int p  = (r5 << 8) | r8;                      // rev13(32t+i)
        xr[i] = re[p]; xi[i] = im[p];
    }
    __syncthreads();
    reg_stage<1,  INV>(xr, xi, tw);
    reg_stage<2,  INV>(xr, xi, tw);
    reg_stage<4,  INV>(xr, xi, tw);
    reg_stage<8,  INV>(xr, xi, tw);
    reg_stage<16, INV>(xr, xi, tw);
    #pragma unroll
    for (int i = 0; i < 32; ++i) { re[32 * t + i] = xr[i]; im[32 * t + i] = xi[i]; }
    __syncthreads();

    #pragma unroll
    for (int s = 0; s < 4; ++s) {
        const int LOG2L = 5 + 2 * s;
        const int L = 1 << LOG2L;                     // 32,128,512,2048
        #pragma unroll
        for (int it = 0; it < 8; ++it) {
            const int m = it * 256 + t;               // butterfly id
            const int j = m & (L - 1);
            const int g = m >> LOG2L;
            const int i0 = (g << (LOG2L + 2)) + j;
            float2 wa = tw[j << (12 - LOG2L)];        // W_{2L}^j
            float2 wb = tw[j << (11 - LOG2L)];        // W_{4L}^j
            float w1r = wa.x, w1i = INV ? -wa.y : wa.y;
            float w2r = wb.x, w2i = INV ? -wb.y : wb.y;
            float pr = re[i0],         pi = im[i0];
            float qr = re[i0 + L],     qi = im[i0 + L];
            float rr_ = re[i0 + 2*L],  ri_ = im[i0 + 2*L];
            float sr = re[i0 + 3*L],   si = im[i0 + 3*L];
            float tqr = qr * w1r - qi * w1i, tqi = qr * w1i + qi * w1r;
            float tsr = sr * w1r - si * w1i, tsi = sr * w1i + si * w1r;
            float apr = pr + tqr, api = pi + tqi;
            float amr = pr - tqr, ami = pi - tqi;
            float bpr = rr_ + tsr, bpi = ri_ + tsi;
            float bmr = rr_ - tsr, bmi = ri_ - tsi;
            float ur = bpr * w2r - bpi * w2i, ui = bpr * w2i + bpi * w2r;
            float vr = bmr * w2r - bmi * w2i, vi = bmr * w2i + bmi * w2r;
            float svr = INV ? -vi : vi;               // (+/-i) * (w2*bm)
            float svi = INV ?  vr : -vr;
            re[i0]         = apr + ur;  im[i0]         = api + ui;
            re[i0 + 2*L]   = apr - ur;  im[i0 + 2*L]   = api - ui;
            re[i0 + L]     = amr + svr; im[i0 + L]     = ami + svi;
            re[i0 + 3*L]   = amr - svr; im[i0 + 3*L]   = ami - svi;
        }
        __syncthreads();
    }
}

// ---------------- V = rfft(a) / 8192, d-pairs packed ----------------
__global__ void __launch_bounds__(256) k_vfft(const float2* __restrict__ aT,
                                              const float2* __restrict__ tw,
                                              float2* __restrict__ V)
{
    __shared__ float re[8192];
    __shared__ float im[8192];
    int blk = blockIdx.x;         // h*32 + p
    int h = blk >> 5, p = blk & 31;
    const float2* ac = aT + (size_t)(h * 32 + p) * 8192;
    int t = threadIdx.x;
    #pragma unroll
    for (int i = 0; i < 32; ++i) {
        int idx = i * 256 + t;
        float2 v = ac[idx];
        re[idx] = v.x; im[idx] = v.y;
    }
    __syncthreads();
    fft8192_lds<false>(re, im, tw);
    const float s = 1.0f / 8192.0f;   // fold inverse-FFT scale into V
    float2* V0 = V + (size_t)(h * 64 + 2 * p) * 4104;
    float2* V1 = V0 + 4104;
    for (int k = t; k <= 4096; k += 256) {
        int km = (8192 - k) & 8191;
        float zr1 = re[k],  zi1 = im[k];
        float zr2 = re[km], zi2 = -im[km];
        float a0r = 0.5f * (zr1 + zr2), a0i = 0.5f * (zi1 + zi2);
        float a1r = 0.5f * (zi1 - zi2), a1i = -0.5f * (zr1 - zr2);
        V0[k] = make_float2(a0r * s, a0i * s);
        V1[k] = make_float2(a1r * s, a1i * s);
    }
}

// ---------------- pack x: (b,h,r,d) -> float2[bh][p][r] ----------------
__global__ void __launch_bounds__(256) k_pack_x(const float* __restrict__ x,
                                                float2* __restrict__ zx)
{
    int blk = blockIdx.x;
    int bh = blk >> 7, rt = blk & 127, r0 = rt << 5;
    __shared__ float tile[64][33];
    const float* xp = x + (size_t)bh * 4096 * 64;
    int tid = threadIdx.x;
    #pragma unroll
    for (int i = 0; i < 8; ++i) {
        int idx = i * 256 + tid;         // (rr,d)
        int rr = idx >> 6, d = idx & 63;
        tile[d][rr] = xp[(size_t)(r0 + rr) * 64 + d];
    }
    __syncthreads();
    float2* zp = zx + (size_t)bh * 32 * 4096;
    #pragma unroll
    for (int i = 0; i < 4; ++i) {
        int idx = i * 256 + tid;         // (p,rr)
        int p = idx >> 5, rr = idx & 31;
        zp[(size_t)p * 4096 + r0 + rr] = make_float2(tile[2 * p][rr], tile[2 * p + 1][rr]);
    }
}

// ---------------- conv: FFT -> xV -> IFFT, in place on zx ----------------
__global__ void __launch_bounds__(256) k_conv(float2* __restrict__ zx,
                                              const float2* __restrict__ V,
                                              const float2* __restrict__ tw)
{
    __shared__ float re[8192];
    __shared__ float im[8192];
    int blk = blockIdx.x;            // bh*32 + p
    int bh = blk >> 5, p = blk & 31, h = bh & 15;
    float2* zc = zx + (size_t)blk * 4096;
    int t = threadIdx.x;
    #pragma unroll
    for (int i = 0; i < 16; ++i) {
        int idx = i * 256 + t;
        float2 v = zc[idx];
        re[idx] = v.x; im[idx] = v.y;
        re[idx + 4096] = 0.0f; im[idx + 4096] = 0.0f;   // zero-pad to 8192
    }
    __syncthreads();
    fft8192_lds<false>(re, im, tw);
    const float2* V0 = V + (size_t)(h * 64 + 2 * p) * 4104;
    const float2* V1 = V0 + 4104;
    for (int k = t; k <= 4096; k += 256) {
        int km = (8192 - k) & 8191;
        float zr1 = re[k],  zi1 = im[k];
        float zr2 = re[km], zi2 = -im[km];
        float x0r = 0.5f * (zr1 + zr2), x0i = 0.5f * (zi1 + zi2);
        float x1r = 0.5f * (zi1 - zi2), x1i = -0.5f * (zr1 - zr2);
        float2 v0 = V0[k], v1 = V1[k];
        float y0r = v0.x * x0r - v0.y * x0i, y0i = v0.x * x0i + v0.y * x0r;
        float y1r = v1.x * x1r - v1.y * x1i, y1i = v1.x * x1i + v1.y * x1r;
        re[k] = y0r - y1i;  im[k] = y0i + y1r;          // Y0 + i*Y1
        if (k > 0 && k < 4096) {                        // conj(Y0) + i*conj(Y1)
            re[km] = y0r + y1i;  im[km] = y1r - y0i;
        }
    }
    __syncthreads();
    fft8192_lds<true>(re, im, tw);
    #pragma unroll
    for (int i = 0; i < 16; ++i) {
        int idx = i * 256 + t;
        zc[idx] = make_float2(re[idx], im[idx]);        // keep first 4096 lags
    }
}

// ---------------- unpack: float2[bh][p][r] -> out(b,h,r,d) ----------------
__global__ void __launch_bounds__(256) k_unpack_out(const float2* __restrict__ zo,
                                                    float* __restrict__ out)
{
    int blk = blockIdx.x;
    int bh = blk >> 7, rt = blk & 127, r0 = rt << 5;
    __shared__ float tile[64][33];
    const float2* zp = zo + (size_t)bh * 32 * 4096;
    int tid = threadIdx.x;
    #pragma unroll
    for (int i = 0; i < 4; ++i) {
        int idx = i * 256 + tid;
        int p = idx >> 5, rr = idx & 31;
        float2 v = zp[(size_t)p * 4096 + r0 + rr];
        tile[2 * p][rr] = v.x; tile[2 * p + 1][rr] = v.y;
    }
    __syncthreads();
    float* op = out + (size_t)bh * 4096 * 64;
    #pragma unroll
    for (int i = 0; i < 8; ++i) {
        int idx = i * 256 + tid;
        int rr = idx >> 6, d = idx & 63;
        op[(size_t)(r0 + rr) * 64 + d] = tile[d][rr];
    }
}

extern "C" void kernel_launch(void* const* d_in, const int* in_sizes, int n_in,
                              void* d_out, int out_size, void* d_ws, size_t ws_size,
                              hipStream_t stream)
{
    (void)in_sizes; (void)n_in; (void)out_size;
    const float* x   = (const float*)d_in[0];
    const float* w0  = (const float*)d_in[1];
    const float* b0  = (const float*)d_in[2];
    const float* g1  = (const float*)d_in[3];
    const float* be1 = (const float*)d_in[4];
    const float* w1  = (const float*)d_in[5];
    const float* b1  = (const float*)d_in[6];
    const float* g2  = (const float*)d_in[7];
    const float* be2 = (const float*)d_in[8];
    const float* w2  = (const float*)d_in[9];
    const float* b2  = (const float*)d_in[10];
    const float* g3  = (const float*)d_in[11];
    const float* be3 = (const float*)d_in[12];
    const float* w3  = (const float*)d_in[13];
    const float* b3  = (const float*)d_in[14];
    float* out = (float*)d_out;
    char* ws = (char*)d_ws;
    if (ws_size < WS_NEED) return;   // ws too small: bench will flag; restructure next round

    float2* tw = (float2*)(ws + OFF_TW);
    float2* V  = (float2*)(ws + OFF_V);
    float2* aT = (float2*)(ws + OFF_AT);
    float2* zx = (float2*)(ws + OFF_ZX);

    k_init_tw<<<16, 256, 0, stream>>>(tw);
    k_dpb<<<131072, 256, 0, stream>>>(w0, b0, g1, be1, w1, b1, g2, be2,
                                      w2, b2, g3, be3, w3, b3, (float*)aT);
    k_vfft<<<512, 256, 0, stream>>>(aT, tw, V);
    k_pack_x<<<16384, 256, 0, stream>>>(x, zx);
    k_conv<<<4096, 256, 0, stream>>>(zx, V, tw);
    k_unpack_out<<<16384, 256, 0, stream>>>((const float2*)zx, out);
}

// Round 2
// 985.835 us; speedup vs baseline: 1.9893x; 1.9893x over previous
//
#include <hip/hip_runtime.h>
#include <math.h>

// ---------------- workspace layout ----------------
// tw  : float2[4096]           W_8192^k = e^{-i pi k/4096}, k<4096
// V   : float2[16][64][4104]   rfft(a)/8192 per (h,d), bins 0..4096
// aT  : float2[16][32][8192]   packed a: aT[h][p][r] = (a[h][r][2p], a[h][r][2p+1])
// zx  : float2[128][32][4096]  packed x columns, reused in-place for output
static const size_t OFF_TW = 0;
static const size_t OFF_V  = 32768;
static const size_t OFF_AT = OFF_V  + (size_t)16 * 64 * 4104 * 8;
static const size_t OFF_ZX = OFF_AT + (size_t)16 * 32 * 8192 * 8;
static const size_t WS_NEED = OFF_ZX + (size_t)128 * 32 * 4096 * 8;

// ---------------- twiddle init ----------------
__global__ void __launch_bounds__(256) k_init_tw(float2* __restrict__ tw)
{
    int k = blockIdx.x * 256 + threadIdx.x;
    if (k < 4096) {
        double a = (double)k * (3.14159265358979323846 / 4096.0);
        tw[k] = make_float2((float)cos(a), (float)(-sin(a)));
    }
}

// ---------------- dpb MLP: lane per evaluation row ----------------
// Each lane owns one (r,dd) evaluation: 64 activations live in VGPRs.
// LayerNorm is pure per-lane math; weights are read with lane-uniform
// indices -> scalar loads (constant cache), zero LDS/shuffle traffic.
__device__ __forceinline__ void ln_relu_arr(float* b,
                                            const float* __restrict__ g,
                                            const float* __restrict__ be)
{
    float s0 = 0, s1 = 0, s2 = 0, s3 = 0;
    #pragma unroll
    for (int k = 0; k < 64; k += 4) {
        s0 += b[k]; s1 += b[k + 1]; s2 += b[k + 2]; s3 += b[k + 3];
    }
    float m = (s0 + s1 + s2 + s3) * (1.0f / 64.0f);
    float v0 = 0, v1 = 0, v2 = 0, v3 = 0;
    #pragma unroll
    for (int k = 0; k < 64; k += 4) {
        float c0 = b[k] - m, c1 = b[k + 1] - m, c2 = b[k + 2] - m, c3 = b[k + 3] - m;
        v0 = fmaf(c0, c0, v0); v1 = fmaf(c1, c1, v1);
        v2 = fmaf(c2, c2, v2); v3 = fmaf(c3, c3, v3);
    }
    float inv = rsqrtf((v0 + v1 + v2 + v3) * (1.0f / 64.0f) + 1e-5f);
    #pragma unroll
    for (int k = 0; k < 64; ++k)
        b[k] = fmaxf(fmaf((b[k] - m) * inv, g[k], be[k]), 0.0f);
}

__device__ __forceinline__ void matmul64(const float* b, float* o,
                                         const float* __restrict__ w,
                                         const float* __restrict__ bias)
{
    #pragma unroll
    for (int j = 0; j < 64; ++j) o[j] = bias[j];
    #pragma unroll 1
    for (int k = 0; k < 64; ++k) {
        float bk = b[k];
        const float* wr = w + (k << 6);
        #pragma unroll
        for (int j = 0; j < 64; ++j) o[j] = fmaf(bk, wr[j], o[j]);
    }
}

__global__ void __launch_bounds__(256) k_dpb(
    const float* __restrict__ w0,  const float* __restrict__ b0,
    const float* __restrict__ g1,  const float* __restrict__ be1,
    const float* __restrict__ w1,  const float* __restrict__ b1,
    const float* __restrict__ g2,  const float* __restrict__ be2,
    const float* __restrict__ w2,  const float* __restrict__ b2,
    const float* __restrict__ g3,  const float* __restrict__ be3,
    const float* __restrict__ w3,  const float* __restrict__ b3,
    float* __restrict__ aTf)
{
    int e  = blockIdx.x * 256 + threadIdx.x;   // 524288 evaluations
    int r  = e & 8191;                         // position along length-8192 'a'
    int dd = e >> 13;                          // dim index 0..63
    const float scale = (float)(1.0 / 262080.0);
    float u;
    if (r == 0 || r == 4096) u = 0.0f;
    else if (r < 4096)       u = (float)((r - 1) * 64 + dd + 1) * scale;
    else                     u = -(float)(262080 - ((r - 4097) * 64 + dd)) * scale;

    float b[64], o[64];
    #pragma unroll
    for (int j = 0; j < 64; ++j) b[j] = fmaf(u, w0[j], b0[j]);

    ln_relu_arr(b, g1, be1);
    matmul64(b, o, w1, b1);
    ln_relu_arr(o, g2, be2);
    matmul64(o, b, w2, b2);
    ln_relu_arr(b, g3, be3);

    float f[16];
    #pragma unroll
    for (int j = 0; j < 16; ++j) f[j] = b3[j];
    #pragma unroll 1
    for (int k = 0; k < 64; ++k) {
        float bk = b[k];
        const float* wr = w3 + (k << 4);
        #pragma unroll
        for (int j = 0; j < 16; ++j) f[j] = fmaf(bk, wr[j], f[j]);
    }
    #pragma unroll
    for (int h = 0; h < 16; ++h) {
        size_t idx = ((size_t)((h << 5) + (dd >> 1)) * 8192 + r) * 2 + (dd & 1);
        aTf[idx] = f[h];
    }
}

// ---------------- LDS bank swizzle ----------------
// phys = A ^ ((A>>5)&31): bijective on [0,8192), size-preserving.
// Makes the register-stage writeback (stride-32, was 64-way conflict) and
// the bit-reversed gather (was 8-way) both 2-way == free.
__device__ __forceinline__ int sw(int a) { return a ^ ((a >> 5) & 31); }

// ---------------- 8192-pt complex FFT in LDS (256 threads) ----------------
// Natural-order in, natural-order out. 5 in-register radix-2 stages (on
// bit-reversed reads) + 4 LDS radix-4 stages (each a fused pair of radix-2
// stages, so plain 13-bit bit-reversal ordering is correct).
// ALL accesses to re/im must go through sw().
template<int L, bool INV>
__device__ __forceinline__ void reg_stage(float* xr, float* xi,
                                          const float2* __restrict__ tw)
{
    #pragma unroll
    for (int b = 0; b < 32; b += 2 * L) {
        #pragma unroll
        for (int j = 0; j < L; ++j) {
            float2 w = tw[j * (4096 / L)];
            float wr = w.x, wi = INV ? -w.y : w.y;
            int i0 = b + j, i1 = b + j + L;
            float tr = xr[i1] * wr - xi[i1] * wi;
            float ti = xr[i1] * wi + xi[i1] * wr;
            xr[i1] = xr[i0] - tr; xi[i1] = xi[i0] - ti;
            xr[i0] += tr;         xi[i0] += ti;
        }
    }
}

template<bool INV>
__device__ __forceinline__ void fft8192_lds(float* re, float* im,
                                            const float2* __restrict__ tw)
{
    const int t  = threadIdx.x;                       // 256 threads
    const int r8 = (int)(__brev((unsigned)t) >> 24);  // rev8(t)
    float xr[32], xi[32];
    #pragma unroll
    for (int i = 0; i < 32; ++i) {
        int r5 = (int)(__brev((unsigned)i) >> 27);    // rev5(i)
        int p  = sw((r5 << 8) | r8);                  // rev13(32t+i), swizzled
        xr[i] = re[p]; xi[i] = im[p];
    }
    __syncthreads();
    reg_stage<1,  INV>(xr, xi, tw);
    reg_stage<2,  INV>(xr, xi, tw);
    reg_stage<4,  INV>(xr, xi, tw);
    reg_stage<8,  INV>(xr, xi, tw);
    reg_stage<16, INV>(xr, xi, tw);
    #pragma unroll
    for (int i = 0; i < 32; ++i) {
        int p = sw(32 * t + i);
        re[p] = xr[i]; im[p] = xi[i];
    }
    __syncthreads();

    #pragma unroll
    for (int s = 0; s < 4; ++s) {
        const int LOG2L = 5 + 2 * s;
        const int L = 1 << LOG2L;                     // 32,128,512,2048
        #pragma unroll
        for (int it = 0; it < 8; ++it) {
            const int m = it * 256 + t;               // butterfly id
            const int j = m & (L - 1);
            const int g = m >> LOG2L;
            const int i0 = (g << (LOG2L + 2)) + j;
            const int p0 = sw(i0), p1 = sw(i0 + L), p2 = sw(i0 + 2 * L), p3 = sw(i0 + 3 * L);
            float2 wa = tw[j << (12 - LOG2L)];        // W_{2L}^j
            float2 wb = tw[j << (11 - LOG2L)];        // W_{4L}^j
            float w1r = wa.x, w1i = INV ? -wa.y : wa.y;
            float w2r = wb.x, w2i = INV ? -wb.y : wb.y;
            float pr = re[p0],  pi = im[p0];
            float qr = re[p1],  qi = im[p1];
            float rr_ = re[p2], ri_ = im[p2];
            float sr = re[p3],  si = im[p3];
            float tqr = qr * w1r - qi * w1i, tqi = qr * w1i + qi * w1r;
            float tsr = sr * w1r - si * w1i, tsi = sr * w1i + si * w1r;
            float apr = pr + tqr, api = pi + tqi;
            float amr = pr - tqr, ami = pi - tqi;
            float bpr = rr_ + tsr, bpi = ri_ + tsi;
            float bmr = rr_ - tsr, bmi = ri_ - tsi;
            float ur = bpr * w2r - bpi * w2i, ui = bpr * w2i + bpi * w2r;
            float vr = bmr * w2r - bmi * w2i, vi = bmr * w2i + bmi * w2r;
            float svr = INV ? -vi : vi;               // (+/-i) * (w2*bm)
            float svi = INV ?  vr : -vr;
            re[p0] = apr + ur;  im[p0] = api + ui;
            re[p2] = apr - ur;  im[p2] = api - ui;
            re[p1] = amr + svr; im[p1] = ami + svi;
            re[p3] = amr - svr; im[p3] = ami - svi;
        }
        __syncthreads();
    }
}

// ---------------- V = rfft(a) / 8192, d-pairs packed ----------------
__global__ void __launch_bounds__(256) k_vfft(const float2* __restrict__ aT,
                                              const float2* __restrict__ tw,
                                              float2* __restrict__ V)
{
    __shared__ float re[8192];
    __shared__ float im[8192];
    int blk = blockIdx.x;         // h*32 + p
    int h = blk >> 5, p = blk & 31;
    const float2* ac = aT + (size_t)(h * 32 + p) * 8192;
    int t = threadIdx.x;
    #pragma unroll
    for (int i = 0; i < 32; ++i) {
        int idx = i * 256 + t;
        float2 v = ac[idx];
        int ps = sw(idx);
        re[ps] = v.x; im[ps] = v.y;
    }
    __syncthreads();
    fft8192_lds<false>(re, im, tw);
    const float s = 1.0f / 8192.0f;   // fold inverse-FFT scale into V
    float2* V0 = V + (size_t)(h * 64 + 2 * p) * 4104;
    float2* V1 = V0 + 4104;
    for (int k = t; k <= 4096; k += 256) {
        int km = (8192 - k) & 8191;
        int pk = sw(k), pm = sw(km);
        float zr1 = re[pk], zi1 = im[pk];
        float zr2 = re[pm], zi2 = -im[pm];
        float a0r = 0.5f * (zr1 + zr2), a0i = 0.5f * (zi1 + zi2);
        float a1r = 0.5f * (zi1 - zi2), a1i = -0.5f * (zr1 - zr2);
        V0[k] = make_float2(a0r * s, a0i * s);
        V1[k] = make_float2(a1r * s, a1i * s);
    }
}

// ---------------- pack x: (b,h,r,d) -> float2[bh][p][r] ----------------
__global__ void __launch_bounds__(256) k_pack_x(const float* __restrict__ x,
                                                float2* __restrict__ zx)
{
    int blk = blockIdx.x;
    int bh = blk >> 7, rt = blk & 127, r0 = rt << 5;
    __shared__ float tile[64][33];
    const float* xp = x + (size_t)bh * 4096 * 64;
    int tid = threadIdx.x;
    #pragma unroll
    for (int i = 0; i < 8; ++i) {
        int idx = i * 256 + tid;         // (rr,d)
        int rr = idx >> 6, d = idx & 63;
        tile[d][rr] = xp[(size_t)(r0 + rr) * 64 + d];
    }
    __syncthreads();
    float2* zp = zx + (size_t)bh * 32 * 4096;
    #pragma unroll
    for (int i = 0; i < 4; ++i) {
        int idx = i * 256 + tid;         // (p,rr)
        int p = idx >> 5, rr = idx & 31;
        zp[(size_t)p * 4096 + r0 + rr] = make_float2(tile[2 * p][rr], tile[2 * p + 1][rr]);
    }
}

// ---------------- conv: FFT -> xV -> IFFT, in place on zx ----------------
__global__ void __launch_bounds__(256) k_conv(float2* __restrict__ zx,
                                              const float2* __restrict__ V,
                                              const float2* __restrict__ tw)
{
    __shared__ float re[8192];
    __shared__ float im[8192];
    int blk = blockIdx.x;            // bh*32 + p
    int bh = blk >> 5, p = blk & 31, h = bh & 15;
    float2* zc = zx + (size_t)blk * 4096;
    int t = threadIdx.x;
    #pragma unroll
    for (int i = 0; i < 16; ++i) {
        int idx = i * 256 + t;
        float2 v = zc[idx];
        int p0 = sw(idx), p1 = sw(idx + 4096);
        re[p0] = v.x; im[p0] = v.y;
        re[p1] = 0.0f; im[p1] = 0.0f;                   // zero-pad to 8192
    }
    __syncthreads();
    fft8192_lds<false>(re, im, tw);
    const float2* V0 = V + (size_t)(h * 64 + 2 * p) * 4104;
    const float2* V1 = V0 + 4104;
    for (int k = t; k <= 4096; k += 256) {
        int km = (8192 - k) & 8191;
        int pk = sw(k), pm = sw(km);
        float zr1 = re[pk], zi1 = im[pk];
        float zr2 = re[pm], zi2 = -im[pm];
        float x0r = 0.5f * (zr1 + zr2), x0i = 0.5f * (zi1 + zi2);
        float x1r = 0.5f * (zi1 - zi2), x1i = -0.5f * (zr1 - zr2);
        float2 v0 = V0[k], v1 = V1[k];
        float y0r = v0.x * x0r - v0.y * x0i, y0i = v0.x * x0i + v0.y * x0r;
        float y1r = v1.x * x1r - v1.y * x1i, y1i = v1.x * x1i + v1.y * x1r;
        re[pk] = y0r - y1i;  im[pk] = y0i + y1r;        // Y0 + i*Y1
        if (k > 0 && k < 4096) {                        // conj(Y0) + i*conj(Y1)
            re[pm] = y0r + y1i;  im[pm] = y1r - y0i;
        }
    }
    __syncthreads();
    fft8192_lds<true>(re, im, tw);
    #pragma unroll
    for (int i = 0; i < 16; ++i) {
        int idx = i * 256 + t;
        int p0 = sw(idx);
        zc[idx] = make_float2(re[p0], im[p0]);          // keep first 4096 lags
    }
}

// ---------------- unpack: float2[bh][p][r] -> out(b,h,r,d) ----------------
__global__ void __launch_bounds__(256) k_unpack_out(const float2* __restrict__ zo,
                                                    float* __restrict__ out)
{
    int blk = blockIdx.x;
    int bh = blk >> 7, rt = blk & 127, r0 = rt << 5;
    __shared__ float tile[64][33];
    const float2* zp = zo + (size_t)bh * 32 * 4096;
    int tid = threadIdx.x;
    #pragma unroll
    for (int i = 0; i < 4; ++i) {
        int idx = i * 256 + tid;
        int p = idx >> 5, rr = idx & 31;
        float2 v = zp[(size_t)p * 4096 + r0 + rr];
        tile[2 * p][rr] = v.x; tile[2 * p + 1][rr] = v.y;
    }
    __syncthreads();
    float* op = out + (size_t)bh * 4096 * 64;
    #pragma unroll
    for (int i = 0; i < 8; ++i) {
        int idx = i * 256 + tid;
        int rr = idx >> 6, d = idx & 63;
        op[(size_t)(r0 + rr) * 64 + d] = tile[d][rr];
    }
}

extern "C" void kernel_launch(void* const* d_in, const int* in_sizes, int n_in,
                              void* d_out, int out_size, void* d_ws, size_t ws_size,
                              hipStream_t stream)
{
    (void)in_sizes; (void)n_in; (void)out_size;
    const float* x   = (const float*)d_in[0];
    const float* w0  = (const float*)d_in[1];
    const float* b0  = (const float*)d_in[2];
    const float* g1  = (const float*)d_in[3];
    const float* be1 = (const float*)d_in[4];
    const float* w1  = (const float*)d_in[5];
    const float* b1  = (const float*)d_in[6];
    const float* g2  = (const float*)d_in[7];
    const float* be2 = (const float*)d_in[8];
    const float* w2  = (const float*)d_in[9];
    const float* b2  = (const float*)d_in[10];
    const float* g3  = (const float*)d_in[11];
    const float* be3 = (const float*)d_in[12];
    const float* w3  = (const float*)d_in[13];
    const float* b3  = (const float*)d_in[14];
    float* out = (float*)d_out;
    char* ws = (char*)d_ws;
    if (ws_size < WS_NEED) return;

    float2* tw = (float2*)(ws + OFF_TW);
    float2* V  = (float2*)(ws + OFF_V);
    float2* aT = (float2*)(ws + OFF_AT);
    float2* zx = (float2*)(ws + OFF_ZX);

    k_init_tw<<<16, 256, 0, stream>>>(tw);
    k_dpb<<<2048, 256, 0, stream>>>(w0, b0, g1, be1, w1, b1, g2, be2,
                                    w2, b2, g3, be3, w3, b3, (float*)aT);
    k_vfft<<<512, 256, 0, stream>>>(aT, tw, V);
    k_pack_x<<<16384, 256, 0, stream>>>(x, zx);
    k_conv<<<4096, 256, 0, stream>>>(zx, V, tw);
    k_unpack_out<<<16384, 256, 0, stream>>>((const float2*)zx, out);
}

// Round 3
// 828.247 us; speedup vs baseline: 2.3677x; 1.1903x over previous
//
#include <hip/hip_runtime.h>
#include <math.h>

// ---------------- workspace layout ----------------
static const size_t OFF_TW = 0;
static const size_t OFF_V  = 32768;
static const size_t OFF_AT = OFF_V  + (size_t)16 * 64 * 4104 * 8;
static const size_t OFF_ZX = OFF_AT + (size_t)16 * 32 * 8192 * 8;
static const size_t WS_NEED = OFF_ZX + (size_t)128 * 32 * 4096 * 8;

// ---------------- twiddle init ----------------
__global__ void __launch_bounds__(256) k_init_tw(float2* __restrict__ tw)
{
    int k = blockIdx.x * 256 + threadIdx.x;
    if (k < 4096) {
        double a = (double)k * (3.14159265358979323846 / 4096.0);
        tw[k] = make_float2((float)cos(a), (float)(-sin(a)));
    }
}

// ---------------- dpb MLP: lane per evaluation row (unchanged) ----------------
__device__ __forceinline__ void ln_relu_arr(float* b,
                                            const float* __restrict__ g,
                                            const float* __restrict__ be)
{
    float s0 = 0, s1 = 0, s2 = 0, s3 = 0;
    #pragma unroll
    for (int k = 0; k < 64; k += 4) {
        s0 += b[k]; s1 += b[k + 1]; s2 += b[k + 2]; s3 += b[k + 3];
    }
    float m = (s0 + s1 + s2 + s3) * (1.0f / 64.0f);
    float v0 = 0, v1 = 0, v2 = 0, v3 = 0;
    #pragma unroll
    for (int k = 0; k < 64; k += 4) {
        float c0 = b[k] - m, c1 = b[k + 1] - m, c2 = b[k + 2] - m, c3 = b[k + 3] - m;
        v0 = fmaf(c0, c0, v0); v1 = fmaf(c1, c1, v1);
        v2 = fmaf(c2, c2, v2); v3 = fmaf(c3, c3, v3);
    }
    float inv = rsqrtf((v0 + v1 + v2 + v3) * (1.0f / 64.0f) + 1e-5f);
    #pragma unroll
    for (int k = 0; k < 64; ++k)
        b[k] = fmaxf(fmaf((b[k] - m) * inv, g[k], be[k]), 0.0f);
}

__device__ __forceinline__ void matmul64(const float* b, float* o,
                                         const float* __restrict__ w,
                                         const float* __restrict__ bias)
{
    #pragma unroll
    for (int j = 0; j < 64; ++j) o[j] = bias[j];
    #pragma unroll 1
    for (int k = 0; k < 64; ++k) {
        float bk = b[k];
        const float* wr = w + (k << 6);
        #pragma unroll
        for (int j = 0; j < 64; ++j) o[j] = fmaf(bk, wr[j], o[j]);
    }
}

__global__ void __launch_bounds__(256) k_dpb(
    const float* __restrict__ w0,  const float* __restrict__ b0,
    const float* __restrict__ g1,  const float* __restrict__ be1,
    const float* __restrict__ w1,  const float* __restrict__ b1,
    const float* __restrict__ g2,  const float* __restrict__ be2,
    const float* __restrict__ w2,  const float* __restrict__ b2,
    const float* __restrict__ g3,  const float* __restrict__ be3,
    const float* __restrict__ w3,  const float* __restrict__ b3,
    float* __restrict__ aTf)
{
    int e  = blockIdx.x * 256 + threadIdx.x;
    int r  = e & 8191;
    int dd = e >> 13;
    const float scale = (float)(1.0 / 262080.0);
    float u;
    if (r == 0 || r == 4096) u = 0.0f;
    else if (r < 4096)       u = (float)((r - 1) * 64 + dd + 1) * scale;
    else                     u = -(float)(262080 - ((r - 4097) * 64 + dd)) * scale;

    float b[64], o[64];
    #pragma unroll
    for (int j = 0; j < 64; ++j) b[j] = fmaf(u, w0[j], b0[j]);

    ln_relu_arr(b, g1, be1);
    matmul64(b, o, w1, b1);
    ln_relu_arr(o, g2, be2);
    matmul64(o, b, w2, b2);
    ln_relu_arr(b, g3, be3);

    float f[16];
    #pragma unroll
    for (int j = 0; j < 16; ++j) f[j] = b3[j];
    #pragma unroll 1
    for (int k = 0; k < 64; ++k) {
        float bk = b[k];
        const float* wr = w3 + (k << 4);
        #pragma unroll
        for (int j = 0; j < 16; ++j) f[j] = fmaf(bk, wr[j], f[j]);
    }
    #pragma unroll
    for (int h = 0; h < 16; ++h) {
        size_t idx = ((size_t)((h << 5) + (dd >> 1)) * 8192 + r) * 2 + (dd & 1);
        aTf[idx] = f[h];
    }
}

// ---------------- LDS swizzle for float2[8192] ----------------
// sw(p) = p ^ ((p>>4)&15) ^ ((p>>8)&1): involution on [0,8192); makes every
// access pattern in the FFT (contiguous fill, bit-reversed gather, stride-32
// writeback, radix-16 stage strides 32/512, k<->8192-k pairing) exactly
// 4 dwords/bank per wave64 ds_*_b64 == conflict-free.
__device__ __forceinline__ int sw(int a)
{
    return a ^ ((a >> 4) & 15) ^ ((a >> 8) & 1);
}

__device__ __forceinline__ float2 cmul(float2 a, float2 b)
{
    return make_float2(fmaf(a.x, b.x, -(a.y * b.y)), fmaf(a.x, b.y, a.y * b.x));
}

// multiply by forward twiddle (wr, wi); INV conjugates the twiddle
template<bool INV>
__device__ __forceinline__ float2 twm(float2 a, float wr, float wi)
{
    float i = INV ? -wi : wi;
    return make_float2(fmaf(a.x, wr, -(a.y * i)), fmaf(a.x, i, a.y * wr));
}

// ---------------- in-register 16-point DIT FFT ----------------
// input z in bit-reversed order, output natural order
template<bool INV>
__device__ __forceinline__ void fft16(float2* z)
{
    const float SQ = 0.70710678118654752440f;
    const float C1 = 0.92387953251128675613f;  // cos(pi/8)
    const float S1 = 0.38268343236508977173f;  // sin(pi/8)
    #pragma unroll
    for (int b = 0; b < 16; b += 2) {
        float2 u = z[b], t = z[b + 1];
        z[b]     = make_float2(u.x + t.x, u.y + t.y);
        z[b + 1] = make_float2(u.x - t.x, u.y - t.y);
    }
    const float w4r[2] = {1.0f, 0.0f};
    const float w4i[2] = {0.0f, -1.0f};
    #pragma unroll
    for (int b = 0; b < 16; b += 4) {
        #pragma unroll
        for (int j = 0; j < 2; ++j) {
            float2 u = z[b + j];
            float2 t = twm<INV>(z[b + j + 2], w4r[j], w4i[j]);
            z[b + j]     = make_float2(u.x + t.x, u.y + t.y);
            z[b + j + 2] = make_float2(u.x - t.x, u.y - t.y);
        }
    }
    const float w8r[4] = {1.0f, SQ, 0.0f, -SQ};
    const float w8i[4] = {0.0f, -SQ, -1.0f, -SQ};
    #pragma unroll
    for (int b = 0; b < 16; b += 8) {
        #pragma unroll
        for (int j = 0; j < 4; ++j) {
            float2 u = z[b + j];
            float2 t = twm<INV>(z[b + j + 4], w8r[j], w8i[j]);
            z[b + j]     = make_float2(u.x + t.x, u.y + t.y);
            z[b + j + 4] = make_float2(u.x - t.x, u.y - t.y);
        }
    }
    const float wgr[8] = {1.0f, C1, SQ, S1, 0.0f, -S1, -SQ, -C1};
    const float wgi[8] = {0.0f, -S1, -SQ, -C1, -1.0f, -C1, -SQ, -S1};
    #pragma unroll
    for (int j = 0; j < 8; ++j) {
        float2 u = z[j];
        float2 t = twm<INV>(z[j + 8], wgr[j], wgi[j]);
        z[j]     = make_float2(u.x + t.x, u.y + t.y);
        z[j + 8] = make_float2(u.x - t.x, u.y - t.y);
    }
}

// ---------------- radix-16 LDS butterfly ----------------
// Fuses 4 radix-2 DIT stages (spans L,2L,4L,8L):
//   out_q = sum_u v[rev4(u)] * W_{16L}^{j*u} * W_16^{q*u}
// tw index scale s: W_{16L} = W_8192^s  (stage A: L=32, s=16; stage B: L=512, s=1)
template<bool INV>
__device__ __forceinline__ void r16(float2* __restrict__ Z, int base, int j, int L, int s,
                                    const float2* __restrict__ tw)
{
    int addr[16];
    #pragma unroll
    for (int m = 0; m < 16; ++m) addr[m] = sw(base + j + L * m);
    float2 t1 = tw[j * s], t2 = tw[2 * j * s], t4 = tw[4 * j * s], t8 = tw[8 * j * s];
    if (INV) { t1.y = -t1.y; t2.y = -t2.y; t4.y = -t4.y; t8.y = -t8.y; }
    float2 T[16];
    T[1] = t1; T[2] = t2; T[4] = t4; T[8] = t8;
    T[3]  = cmul(t1, t2);   T[5]  = cmul(t1, t4);   T[6]  = cmul(t2, t4);
    T[7]  = cmul(T[3], t4); T[9]  = cmul(t1, t8);   T[10] = cmul(t2, t8);
    T[11] = cmul(T[3], t8); T[12] = cmul(t4, t8);   T[13] = cmul(T[5], t8);
    T[14] = cmul(T[6], t8); T[15] = cmul(T[7], t8);
    const int rv[16] = {0, 8, 4, 12, 2, 10, 6, 14, 1, 9, 5, 13, 3, 11, 7, 15};
    float2 z[16];
    z[0] = Z[addr[0]];
    #pragma unroll
    for (int m = 1; m < 16; ++m) z[m] = cmul(Z[addr[m]], T[rv[m]]);
    fft16<INV>(z);
    #pragma unroll
    for (int q = 0; q < 16; ++q) Z[addr[q]] = z[q];
}

// ---------------- first 5 stages in registers (unchanged math) ----------------
template<int L, bool INV>
__device__ __forceinline__ void reg_stage(float* xr, float* xi,
                                          const float2* __restrict__ tw)
{
    #pragma unroll
    for (int b = 0; b < 32; b += 2 * L) {
        #pragma unroll
        for (int j = 0; j < L; ++j) {
            float2 w = tw[j * (4096 / L)];
            float wr = w.x, wi = INV ? -w.y : w.y;
            int i0 = b + j, i1 = b + j + L;
            float tr = xr[i1] * wr - xi[i1] * wi;
            float ti = xr[i1] * wi + xi[i1] * wr;
            xr[i1] = xr[i0] - tr; xi[i1] = xi[i0] - ti;
            xr[i0] += tr;         xi[i0] += ti;
        }
    }
}

// ---------------- 8192-pt complex FFT: natural in/out ----------------
// Caller must __syncthreads() after populating Z and before calling.
template<bool INV>
__device__ __forceinline__ void fft8192_lds(float2* __restrict__ Z,
                                            const float2* __restrict__ tw)
{
    const int t  = threadIdx.x;                       // 256 threads
    const int r8 = (int)(__brev((unsigned)t) >> 24);  // rev8(t)
    float xr[32], xi[32];
    #pragma unroll
    for (int i = 0; i < 32; ++i) {
        int r5 = (int)(__brev((unsigned)i) >> 27);    // rev5(i)
        float2 v = Z[sw((r5 << 8) | r8)];             // rev13(32t+i)
        xr[i] = v.x; xi[i] = v.y;
    }
    __syncthreads();
    reg_stage<1,  INV>(xr, xi, tw);
    reg_stage<2,  INV>(xr, xi, tw);
    reg_stage<4,  INV>(xr, xi, tw);
    reg_stage<8,  INV>(xr, xi, tw);
    reg_stage<16, INV>(xr, xi, tw);
    #pragma unroll
    for (int i = 0; i < 32; ++i) Z[sw(32 * t + i)] = make_float2(xr[i], xi[i]);
    __syncthreads();
    // stage A: spans 32..256, groups of 512
    {
        int j = t & 31, g = t >> 5;
        r16<INV>(Z, g * 512, j, 32, 16, tw);
        r16<INV>(Z, (g + 8) * 512, j, 32, 16, tw);
    }
    __syncthreads();
    // stage B: spans 512..4096, single group of 8192
    r16<INV>(Z, 0, t, 512, 1, tw);
    r16<INV>(Z, 0, t + 256, 512, 1, tw);
    __syncthreads();
}

// ---------------- V = rfft(a) / 8192, d-pairs packed ----------------
__global__ void __launch_bounds__(256, 2) k_vfft(const float2* __restrict__ aT,
                                                 const float2* __restrict__ tw,
                                                 float2* __restrict__ V)
{
    __shared__ float2 Z[8192];
    int blk = blockIdx.x;         // h*32 + p
    int h = blk >> 5, p = blk & 31;
    const float2* ac = aT + (size_t)(h * 32 + p) * 8192;
    int t = threadIdx.x;
    #pragma unroll
    for (int i = 0; i < 32; ++i) {
        int idx = i * 256 + t;
        Z[sw(idx)] = ac[idx];
    }
    __syncthreads();
    fft8192_lds<false>(Z, tw);
    const float s = 1.0f / 8192.0f;
    float2* V0 = V + (size_t)(h * 64 + 2 * p) * 4104;
    float2* V1 = V0 + 4104;
    for (int k = t; k <= 4096; k += 256) {
        int km = (8192 - k) & 8191;
        float2 z1 = Z[sw(k)], z2 = Z[sw(km)];
        float zr1 = z1.x, zi1 = z1.y;
        float zr2 = z2.x, zi2 = -z2.y;
        float a0r = 0.5f * (zr1 + zr2), a0i = 0.5f * (zi1 + zi2);
        float a1r = 0.5f * (zi1 - zi2), a1i = -0.5f * (zr1 - zr2);
        V0[k] = make_float2(a0r * s, a0i * s);
        V1[k] = make_float2(a1r * s, a1i * s);
    }
}

// ---------------- pack x: (b,h,r,d) -> float2[bh][p][r] ----------------
__global__ void __launch_bounds__(256) k_pack_x(const float* __restrict__ x,
                                                float2* __restrict__ zx)
{
    int blk = blockIdx.x;
    int bh = blk >> 7, rt = blk & 127, r0 = rt << 5;
    __shared__ float tile[64][33];
    const float* xp = x + (size_t)bh * 4096 * 64;
    int tid = threadIdx.x;
    #pragma unroll
    for (int i = 0; i < 8; ++i) {
        int idx = i * 256 + tid;
        int rr = idx >> 6, d = idx & 63;
        tile[d][rr] = xp[(size_t)(r0 + rr) * 64 + d];
    }
    __syncthreads();
    float2* zp = zx + (size_t)bh * 32 * 4096;
    #pragma unroll
    for (int i = 0; i < 4; ++i) {
        int idx = i * 256 + tid;
        int p = idx >> 5, rr = idx & 31;
        zp[(size_t)p * 4096 + r0 + rr] = make_float2(tile[2 * p][rr], tile[2 * p + 1][rr]);
    }
}

// ---------------- conv: FFT -> xV -> IFFT, in place on zx ----------------
__global__ void __launch_bounds__(256, 2) k_conv(float2* __restrict__ zx,
                                                 const float2* __restrict__ V,
                                                 const float2* __restrict__ tw)
{
    __shared__ float2 Z[8192];
    int blk = blockIdx.x;            // bh*32 + p
    int bh = blk >> 5, p = blk & 31, h = bh & 15;
    float2* zc = zx + (size_t)blk * 4096;
    int t = threadIdx.x;
    #pragma unroll
    for (int i = 0; i < 16; ++i) {
        int idx = i * 256 + t;
        Z[sw(idx)] = zc[idx];
        Z[sw(idx + 4096)] = make_float2(0.0f, 0.0f);    // zero-pad to 8192
    }
    __syncthreads();
    fft8192_lds<false>(Z, tw);
    const float2* V0 = V + (size_t)(h * 64 + 2 * p) * 4104;
    const float2* V1 = V0 + 4104;
    for (int k = t; k <= 4096; k += 256) {
        int km = (8192 - k) & 8191;
        float2 z1 = Z[sw(k)], z2 = Z[sw(km)];
        float zr1 = z1.x, zi1 = z1.y;
        float zr2 = z2.x, zi2 = -z2.y;
        float x0r = 0.5f * (zr1 + zr2), x0i = 0.5f * (zi1 + zi2);
        float x1r = 0.5f * (zi1 - zi2), x1i = -0.5f * (zr1 - zr2);
        float2 v0 = V0[k], v1 = V1[k];
        float y0r = v0.x * x0r - v0.y * x0i, y0i = v0.x * x0i + v0.y * x0r;
        float y1r = v1.x * x1r - v1.y * x1i, y1i = v1.x * x1i + v1.y * x1r;
        Z[sw(k)] = make_float2(y0r - y1i, y0i + y1r);   // Y0 + i*Y1
        if (k > 0 && k < 4096)                          // conj at mirror bin
            Z[sw(km)] = make_float2(y0r + y1i, y1r - y0i);
    }
    __syncthreads();
    fft8192_lds<true>(Z, tw);
    #pragma unroll
    for (int i = 0; i < 16; ++i) {
        int idx = i * 256 + t;
        zc[idx] = Z[sw(idx)];                           // keep first 4096 lags
    }
}

// ---------------- unpack: float2[bh][p][r] -> out(b,h,r,d) ----------------
__global__ void __launch_bounds__(256) k_unpack_out(const float2* __restrict__ zo,
                                                    float* __restrict__ out)
{
    int blk = blockIdx.x;
    int bh = blk >> 7, rt = blk & 127, r0 = rt << 5;
    __shared__ float tile[64][33];
    const float2* zp = zo + (size_t)bh * 32 * 4096;
    int tid = threadIdx.x;
    #pragma unroll
    for (int i = 0; i < 4; ++i) {
        int idx = i * 256 + tid;
        int p = idx >> 5, rr = idx & 31;
        float2 v = zp[(size_t)p * 4096 + r0 + rr];
        tile[2 * p][rr] = v.x; tile[2 * p + 1][rr] = v.y;
    }
    __syncthreads();
    float* op = out + (size_t)bh * 4096 * 64;
    #pragma unroll
    for (int i = 0; i < 8; ++i) {
        int idx = i * 256 + tid;
        int rr = idx >> 6, d = idx & 63;
        op[(size_t)(r0 + rr) * 64 + d] = tile[d][rr];
    }
}

extern "C" void kernel_launch(void* const* d_in, const int* in_sizes, int n_in,
                              void* d_out, int out_size, void* d_ws, size_t ws_size,
                              hipStream_t stream)
{
    (void)in_sizes; (void)n_in; (void)out_size;
    const float* x   = (const float*)d_in[0];
    const float* w0  = (const float*)d_in[1];
    const float* b0  = (const float*)d_in[2];
    const float* g1  = (const float*)d_in[3];
    const float* be1 = (const float*)d_in[4];
    const float* w1  = (const float*)d_in[5];
    const float* b1  = (const float*)d_in[6];
    const float* g2  = (const float*)d_in[7];
    const float* be2 = (const float*)d_in[8];
    const float* w2  = (const float*)d_in[9];
    const float* b2  = (const float*)d_in[10];
    const float* g3  = (const float*)d_in[11];
    const float* be3 = (const float*)d_in[12];
    const float* w3  = (const float*)d_in[13];
    const float* b3  = (const float*)d_in[14];
    float* out = (float*)d_out;
    char* ws = (char*)d_ws;
    if (ws_size < WS_NEED) return;

    float2* tw = (float2*)(ws + OFF_TW);
    float2* V  = (float2*)(ws + OFF_V);
    float2* aT = (float2*)(ws + OFF_AT);
    float2* zx = (float2*)(ws + OFF_ZX);

    k_init_tw<<<16, 256, 0, stream>>>(tw);
    k_dpb<<<2048, 256, 0, stream>>>(w0, b0, g1, be1, w1, b1, g2, be2,
                                    w2, b2, g3, be3, w3, b3, (float*)aT);
    k_vfft<<<512, 256, 0, stream>>>(aT, tw, V);
    k_pack_x<<<16384, 256, 0, stream>>>(x, zx);
    k_conv<<<4096, 256, 0, stream>>>(zx, V, tw);
    k_unpack_out<<<16384, 256, 0, stream>>>((const float2*)zx, out);
}